// Round 3
// baseline (122.357 us; speedup 1.0000x reference)
//
#include <hip/hip_runtime.h>

// Problem dims (fixed by setup_inputs)
#define BS 8
#define NF 16
#define NI 24
#define LL 16384   // 128*128

// Workspace layout (floats)
#define OFF_COUNTS 0                 // [BS][NI]        192
#define OFF_SUMS   192               // [BS][NI][NF]   3072
#define OFF_MEANS  3264              // [BS][NI][NF]   3072
#define OFF_VDEN   6336              // [BS]
#define OFF_DIST   6344              // [BS]
#define OFF_REG    6352              // [BS]
#define OFF_VNUM   6360              // [BS]
#define WS_FLOATS  6368

#define L_CHUNKS 32   // l-chunks per batch in k_sums (chunk = 512 px)
#define I_PER 3       // instances per wave (8 waves x 3 = 24)
#define VBLK 16       // blocks per batch in k_var (4 px/thread)

__device__ __forceinline__ float block_sum(float v, volatile float* red) {
    for (int off = 32; off; off >>= 1) v += __shfl_down(v, off);
    __syncthreads();
    if ((threadIdx.x & 63) == 0) red[threadIdx.x >> 6] = v;
    __syncthreads();
    float r = 0.f;
    int nw = blockDim.x >> 6;
    if ((int)threadIdx.x < nw) r = red[threadIdx.x];
    if ((threadIdx.x >> 6) == 0)
        for (int off = 32; off; off >>= 1) r += __shfl_down(r, off);
    return r;  // valid in thread 0
}

// Kernel 1: counts[b,i], sums[b,i,f] = sum_l gt[b,i,l] * pred[b,l,f]
// Register-accumulating scan: wave owns I_PER instance rows, lane owns 4 px.
__global__ __launch_bounds__(512) void k_sums(const float* __restrict__ input,
                                              const int* __restrict__ target,
                                              float* __restrict__ ws) {
    const int b    = blockIdx.y;
    const int w    = threadIdx.x >> 6;    // wave 0..7
    const int lane = threadIdx.x & 63;
    const int i0   = w * I_PER;           // this wave's instance rows
    const int l0   = blockIdx.x * (LL / L_CHUNKS);
    const float* inb = input + (size_t)b * NF * LL;
    const int*   tgb = target + (size_t)b * NI * LL;

    float acc[I_PER][NF];
    float cnt[I_PER];
    #pragma unroll
    for (int ii = 0; ii < I_PER; ++ii) {
        cnt[ii] = 0.f;
        #pragma unroll
        for (int f = 0; f < NF; ++f) acc[ii][f] = 0.f;
    }

    #pragma unroll
    for (int step = 0; step < (LL / L_CHUNKS) / 256; ++step) {  // 2 steps
        const int l = l0 + step * 256 + lane * 4;
        float4 p[NF];
        #pragma unroll
        for (int f = 0; f < NF; ++f)
            p[f] = *reinterpret_cast<const float4*>(inb + f * LL + l);
        #pragma unroll
        for (int ii = 0; ii < I_PER; ++ii) {
            int4 tv = *reinterpret_cast<const int4*>(tgb + (i0 + ii) * LL + l);
            float t0 = (float)tv.x, t1 = (float)tv.y, t2 = (float)tv.z, t3 = (float)tv.w;
            cnt[ii] += (t0 + t1) + (t2 + t3);
            #pragma unroll
            for (int f = 0; f < NF; ++f) {
                float a = acc[ii][f];
                a = fmaf(t0, p[f].x, a);
                a = fmaf(t1, p[f].y, a);
                a = fmaf(t2, p[f].z, a);
                a = fmaf(t3, p[f].w, a);
                acc[ii][f] = a;
            }
        }
    }

    // wave-level butterfly reduce (64 lanes)
    #pragma unroll
    for (int ii = 0; ii < I_PER; ++ii) {
        #pragma unroll
        for (int f = 0; f < NF; ++f)
            for (int off = 32; off; off >>= 1)
                acc[ii][f] += __shfl_down(acc[ii][f], off);
        for (int off = 32; off; off >>= 1)
            cnt[ii] += __shfl_down(cnt[ii], off);
    }
    if (lane == 0) {
        #pragma unroll
        for (int ii = 0; ii < I_PER; ++ii) {
            #pragma unroll
            for (int f = 0; f < NF; ++f)
                atomicAdd(&ws[OFF_SUMS + (b * NI + i0 + ii) * NF + f], acc[ii][f]);
            atomicAdd(&ws[OFF_COUNTS + b * NI + i0 + ii], cnt[ii]);
        }
    }
}

// Kernel 2: means, var_den, dist term, reg term (one block per batch)
__global__ __launch_bounds__(256) void k_means_dist_reg(const int* __restrict__ n_objects,
                                                        float* __restrict__ ws) {
    const int b = blockIdx.x;
    const int t = threadIdx.x;
    const int n = n_objects[b];
    __shared__ float m_lds[NI][NF];
    __shared__ float red[8];

    for (int idx = t; idx < NI * NF; idx += 256) {
        int i = idx >> 4, f = idx & 15;
        float c = ws[OFF_COUNTS + b * NI + i];
        float s = ws[OFF_SUMS + (b * NI + i) * NF + f];
        float m = (i < n) ? s / (c > 0.f ? c : 1.f) : 0.f;
        m_lds[i][f] = m;
        ws[OFF_MEANS + (b * NI + i) * NF + f] = m;
    }
    __syncthreads();

    float vden = 0.f, reg = 0.f;
    if (t < NI && t < n) {
        vden = ws[OFF_COUNTS + b * NI + t];
        float ss = 0.f;
        #pragma unroll
        for (int f = 0; f < NF; ++f) { float m = m_lds[t][f]; ss += m * m; }
        reg = (ss > 0.f) ? sqrtf(ss) : 0.f;
    }
    float dist = 0.f;
    for (int p = t; p < NI * NI; p += 256) {
        int i = p / NI, j = p % NI;
        if (i != j && i < n && j < n) {
            float ss = 0.f;
            #pragma unroll
            for (int f = 0; f < NF; ++f) { float d = m_lds[i][f] - m_lds[j][f]; ss += d * d; }
            float dn = (ss > 0.f) ? sqrtf(ss) : 0.f;
            float h = fmaxf(3.0f - dn, 0.f);  // margin = 2*DELTA_D
            dist += h * h;
        }
    }
    float vden_s = block_sum(vden, red);
    float reg_s  = block_sum(reg, red);
    float dist_s = block_sum(dist, red);
    if (t == 0) {
        ws[OFF_VDEN + b] = vden_s;
        ws[OFF_REG + b]  = reg_s / (float)n;
        float nf = (float)n;
        ws[OFF_DIST + b] = (n > 1) ? dist_s / (nf * (nf - 1.f)) : 0.f;
    }
}

// Kernel 3: variance term numerator — 4 px per thread, vectorized loads
__global__ __launch_bounds__(256) void k_var(const float* __restrict__ input,
                                             const int* __restrict__ target,
                                             const int* __restrict__ n_objects,
                                             float* __restrict__ ws) {
    const int b = blockIdx.y;
    const int n = n_objects[b];
    const int t = threadIdx.x;
    __shared__ float m_lds[NI][NF];
    __shared__ float red[8];
    for (int idx = t; idx < NI * NF; idx += 256)
        m_lds[idx >> 4][idx & 15] = ws[OFF_MEANS + b * NI * NF + idx];
    __syncthreads();

    const float* inb = input + (size_t)b * NF * LL;
    const int*   tgb = target + (size_t)b * NI * LL;
    // one 4-px group per thread: VBLK*256 threads * 4 px = 16384 = LL
    const int l = (blockIdx.x * 256 + t) * 4;

    float4 p[NF];
    #pragma unroll
    for (int f = 0; f < NF; ++f)
        p[f] = *reinterpret_cast<const float4*>(inb + f * LL + l);

    float acc = 0.f;
    for (int i = 0; i < n; ++i) {
        int4 tv = *reinterpret_cast<const int4*>(tgb + i * LL + l);
        float s0 = 0.f, s1 = 0.f, s2 = 0.f, s3 = 0.f;
        #pragma unroll
        for (int f = 0; f < NF; ++f) {
            float m = m_lds[i][f];
            float d0 = p[f].x - m, d1 = p[f].y - m, d2 = p[f].z - m, d3 = p[f].w - m;
            s0 = fmaf(d0, d0, s0); s1 = fmaf(d1, d1, s1);
            s2 = fmaf(d2, d2, s2); s3 = fmaf(d3, d3, s3);
        }
        float h0 = fmaxf(sqrtf(s0) - 0.5f, 0.f);
        float h1 = fmaxf(sqrtf(s1) - 0.5f, 0.f);
        float h2 = fmaxf(sqrtf(s2) - 0.5f, 0.f);
        float h3 = fmaxf(sqrtf(s3) - 0.5f, 0.f);
        acc = fmaf((float)tv.x, h0 * h0, acc);
        acc = fmaf((float)tv.y, h1 * h1, acc);
        acc = fmaf((float)tv.z, h2 * h2, acc);
        acc = fmaf((float)tv.w, h3 * h3, acc);
    }
    float s = block_sum(acc, red);
    if (t == 0) atomicAdd(&ws[OFF_VNUM + b], s);
}

// Kernel 4: combine into scalar
__global__ void k_final(const float* __restrict__ ws, float* __restrict__ out) {
    if (threadIdx.x == 0 && blockIdx.x == 0) {
        float vt = 0.f, dt = 0.f, rt = 0.f;
        for (int b = 0; b < BS; ++b) {
            vt += ws[OFF_VNUM + b] / ws[OFF_VDEN + b];
            dt += ws[OFF_DIST + b];
            rt += ws[OFF_REG + b];
        }
        out[0] = (1.0f * vt + 1.0f * dt + 0.001f * rt) * (1.0f / (float)BS);
    }
}

extern "C" void kernel_launch(void* const* d_in, const int* in_sizes, int n_in,
                              void* d_out, int out_size, void* d_ws, size_t ws_size,
                              hipStream_t stream) {
    const float* input     = (const float*)d_in[0];
    const int*   target    = (const int*)d_in[1];
    const int*   n_objects = (const int*)d_in[2];
    float* ws  = (float*)d_ws;
    float* out = (float*)d_out;

    hipMemsetAsync(d_ws, 0, WS_FLOATS * sizeof(float), stream);

    dim3 gA(L_CHUNKS, BS);
    k_sums<<<gA, 512, 0, stream>>>(input, target, ws);
    k_means_dist_reg<<<BS, 256, 0, stream>>>(n_objects, ws);
    dim3 gC(VBLK, BS);
    k_var<<<gC, 256, 0, stream>>>(input, target, n_objects, ws);
    k_final<<<1, 64, 0, stream>>>(ws, out);
}